// Round 2
// baseline (144.798 us; speedup 1.0000x reference)
//
#include <hip/hip_runtime.h>

// EncoderLayer: B=4, S=2048, D=512, H=8, HD=64. fp32 I/O, bf16 MFMA compute.
// M = B*S = 8192 tokens. GEMMs: [8192,*] = [8192,512] @ W[*,512]^T.

typedef short s16x8 __attribute__((ext_vector_type(8)));
typedef float f32x4 __attribute__((ext_vector_type(4)));
typedef unsigned short u16;
typedef u16 u16x4 __attribute__((ext_vector_type(4)));

__device__ __forceinline__ u16 f2b(float f) {          // fp32 -> bf16 RNE
  union { float f; unsigned u; } c; c.f = f;
  return (u16)((c.u + 0x7FFFu + ((c.u >> 16) & 1u)) >> 16);
}

__device__ __forceinline__ f32x4 mfma16(s16x8 a, s16x8 b, f32x4 c) {
  return __builtin_amdgcn_mfma_f32_16x16x32_bf16(a, b, c, 0, 0, 0);
}

// async global->LDS, 16B per lane; dest = wave-uniform base + lane*16
__device__ __forceinline__ void gload_lds16(const u16* g, u16* l) {
  __builtin_amdgcn_global_load_lds(
      (const __attribute__((address_space(1))) unsigned*)g,
      (__attribute__((address_space(3))) unsigned*)l, 16, 0, 0);
}

// ---------------- weight cast: 6 x [512x512] fp32 -> bf16 (contiguous dst) --
__global__ __launch_bounds__(256) void cast_w(
    const float* __restrict__ s0, const float* __restrict__ s1,
    const float* __restrict__ s2, const float* __restrict__ s3,
    const float* __restrict__ s4, const float* __restrict__ s5,
    u16* __restrict__ dst)
{
  int i = blockIdx.x * 256 + threadIdx.x;   // float4 index, 65536 per matrix
  const float* s;
  switch (blockIdx.y) {
    case 0: s = s0; break; case 1: s = s1; break; case 2: s = s2; break;
    case 3: s = s3; break; case 4: s = s4; break; default: s = s5; break;
  }
  float4 v = ((const float4*)s)[i];
  u16x4 o; o.x = f2b(v.x); o.y = f2b(v.y); o.z = f2b(v.z); o.w = f2b(v.w);
  *(u16x4*)(dst + (size_t)blockIdx.y * 262144 + (size_t)i * 4) = o;
}

// ---------------- LayerNorm (torch: unbiased var, a*(x-mean)/(std+eps)+b) ---
template<int OF, int OB>
__global__ __launch_bounds__(256) void ln_kernel(
    const float* __restrict__ x, const float* __restrict__ ga,
    const float* __restrict__ gbv, float* __restrict__ yf, u16* __restrict__ yb)
{
  int row = blockIdx.x * 4 + (threadIdx.x >> 6);   // one wave per row
  int lane = threadIdx.x & 63;
  size_t base = (size_t)row * 512 + lane * 8;
  const float4* xr = (const float4*)(x + base);
  float4 v0 = xr[0], v1 = xr[1];
  float s  = v0.x + v0.y + v0.z + v0.w + v1.x + v1.y + v1.z + v1.w;
  float ss = v0.x*v0.x + v0.y*v0.y + v0.z*v0.z + v0.w*v0.w
           + v1.x*v1.x + v1.y*v1.y + v1.z*v1.z + v1.w*v1.w;
  #pragma unroll
  for (int m = 1; m < 64; m <<= 1) { s += __shfl_xor(s, m); ss += __shfl_xor(ss, m); }
  float mean = s * (1.0f / 512.0f);
  float var  = fmaxf((ss - 512.0f * mean * mean) * (1.0f / 511.0f), 0.0f);
  float inv  = 1.0f / (sqrtf(var) + 1e-6f);
  const float4* ap = (const float4*)(ga + lane * 8);
  const float4* bp = (const float4*)(gbv + lane * 8);
  float4 a0 = ap[0], a1 = ap[1], b0 = bp[0], b1 = bp[1];
  float4 y0, y1;
  y0.x = (v0.x-mean)*inv*a0.x + b0.x;  y0.y = (v0.y-mean)*inv*a0.y + b0.y;
  y0.z = (v0.z-mean)*inv*a0.z + b0.z;  y0.w = (v0.w-mean)*inv*a0.w + b0.w;
  y1.x = (v1.x-mean)*inv*a1.x + b1.x;  y1.y = (v1.y-mean)*inv*a1.y + b1.y;
  y1.z = (v1.z-mean)*inv*a1.z + b1.z;  y1.w = (v1.w-mean)*inv*a1.w + b1.w;
  if (OF) { float4* o = (float4*)(yf + base); o[0] = y0; o[1] = y1; }
  if (OB) {
    union { s16x8 v; u16 u[8]; } pk;
    pk.u[0]=f2b(y0.x); pk.u[1]=f2b(y0.y); pk.u[2]=f2b(y0.z); pk.u[3]=f2b(y0.w);
    pk.u[4]=f2b(y1.x); pk.u[5]=f2b(y1.y); pk.u[6]=f2b(y1.z); pk.u[7]=f2b(y1.w);
    *(s16x8*)(yb + base) = pk.v;
  }
}

// ---------------- GEMM 128x128 tile, 3-buffer counted-vmcnt pipeline --------
// C[8192,N] = A[8192,512](bf16) @ W[N,512]^T, N = 512 or 1536 (fused QKV).
// 4 waves (2x2), each owns 64x64; BK=32. T3/T4: 2-deep prefetch into 3 LDS
// buffers, raw s_barrier + counted s_waitcnt vmcnt(4) (4 gload_lds/wave per
// tile; 2 tiles in flight) -> loads stay in flight across barriers instead
// of the __syncthreads vmcnt(0) drain. Bank-swizzle chunk^=(row>>1)&3.
// MODE bits: 1=bias, 2=relu, 4=resid(fp32), 8=store f32, 16=store bf16,
//            64=fused QKV epilogue (q scaled, k plain, v permuted-transpose)
template<int MODE>
__global__ __launch_bounds__(256) void gemm128(
    const u16* __restrict__ A, const u16* __restrict__ W,
    const float* __restrict__ bias, const float* __restrict__ resid,
    float* __restrict__ outf, u16* __restrict__ outb,
    u16* __restrict__ outb2, u16* __restrict__ outb3, float qscale)
{
  __shared__ u16 als[3][128 * 32];             // 8KB per buf, 48KB total
  __shared__ u16 bls[3][128 * 32];
  int t = threadIdx.x, lane = t & 63, w = t >> 6;
  int l15 = lane & 15, g = lane >> 4;
  int wr = w >> 1, wc = w & 1;
  int mbase = blockIdx.x * 128, nbase = blockIdx.y * 128;

  // staging: chunkid = i*256+t -> row=cid>>2, phys chunk=cid&3,
  // source (logical) chunk = (cid&3) ^ ((row>>1)&3)
  int r0 = t >> 2, cs = (t & 3) ^ ((r0 >> 1) & 3);  // note: same cs for row+64
  size_t offA0 = (size_t)(mbase + r0) * 512 + cs * 8;
  size_t offA1 = (size_t)(mbase + r0 + 64) * 512 + cs * 8;
  size_t offB0 = (size_t)(nbase + r0) * 512 + cs * 8;
  size_t offB1 = (size_t)(nbase + r0 + 64) * 512 + cs * 8;

  #define GSTAGE(buf, k0) do {                                    \
    gload_lds16(A + (k0) + offA0, &als[buf][(w * 64) * 8]);       \
    gload_lds16(A + (k0) + offA1, &als[buf][(256 + w * 64) * 8]); \
    gload_lds16(W + (k0) + offB0, &bls[buf][(w * 64) * 8]);       \
    gload_lds16(W + (k0) + offB1, &bls[buf][(256 + w * 64) * 8]); \
  } while (0)

  // fragment ds_read offsets (u16 units), logical chunk g swizzled per row
  int ar[4], br[4];
  #pragma unroll
  for (int i = 0; i < 4; ++i) {
    int rA = wr * 64 + i * 16 + l15;
    ar[i] = rA * 32 + ((g ^ ((rA >> 1) & 3)) << 3);
    int rB = wc * 64 + i * 16 + l15;
    br[i] = rB * 32 + ((g ^ ((rB >> 1) & 3)) << 3);
  }

  f32x4 zero = {0.0f, 0.0f, 0.0f, 0.0f};
  f32x4 acc[4][4];
  #pragma unroll
  for (int mi = 0; mi < 4; ++mi)
    #pragma unroll
    for (int ni = 0; ni < 4; ++ni) acc[mi][ni] = zero;

  GSTAGE(0, 0);                                // tiles 0,1 in flight
  GSTAGE(1, 32);
  int bi = 0;
  for (int kk = 0; kk < 16; ++kk) {
    // tile kk landed when <=4 of this wave's loads remain (the newest tile)
    if (kk < 15) asm volatile("s_waitcnt vmcnt(4)" ::: "memory");
    else         asm volatile("s_waitcnt vmcnt(0)" ::: "memory");
    __builtin_amdgcn_s_barrier();              // also: buf (bi+2)%3 free now
    if (kk + 2 < 16) {
      int pi = bi + 2; if (pi >= 3) pi -= 3;
      GSTAGE(pi, (kk + 2) * 32);
    }
    const u16* acur = als[bi];
    const u16* bcur = bls[bi];
    s16x8 af[4], bfr[4];
    #pragma unroll
    for (int i = 0; i < 4; ++i) {
      af[i]  = *(const s16x8*)&acur[ar[i]];
      bfr[i] = *(const s16x8*)&bcur[br[i]];
    }
    #pragma unroll
    for (int mi = 0; mi < 4; ++mi)
      #pragma unroll
      for (int ni = 0; ni < 4; ++ni)
        acc[mi][ni] = mfma16(af[mi], bfr[ni], acc[mi][ni]);
    bi = (bi == 2) ? 0 : bi + 1;
  }
  #undef GSTAGE

  #pragma unroll
  for (int ni = 0; ni < 4; ++ni) {
    int n = nbase + wc * 64 + ni * 16 + l15;
    float bv = (MODE & 1) ? bias[n] : 0.0f;
    #pragma unroll
    for (int mi = 0; mi < 4; ++mi) {
      #pragma unroll
      for (int r = 0; r < 4; ++r) {
        int m = mbase + wr * 64 + mi * 16 + 4 * g + r;  // D: col=l15, row=4g+r
        float v = acc[mi][ni][r] + bv;
        if (MODE & 2) v = fmaxf(v, 0.0f);
        if (MODE & 4) v += resid[(size_t)m * 512 + n];
        if (MODE & 8) outf[(size_t)m * 512 + n] = v;
        if (MODE & 16) outb[(size_t)m * 512 + n] = f2b(v);
        if (MODE & 64) {
          if (nbase < 512) {                       // Q (pre-scaled)
            outb[(size_t)m * 512 + n] = f2b(v * qscale);
          } else if (nbase < 1024) {               // K
            outb2[(size_t)m * 512 + (n - 512)] = f2b(v);
          } else {                                 // V^T with attn k-perm
            int nn = n - 1024;
            int sidx = m & 2047;
            int jj = sidx & 31, lo4 = jj & 15, b5 = jj >> 4;
            int pos = ((lo4 >> 2) << 3) + ((lo4 & 3) << 1) + b5;
            outb3[(size_t)((m >> 11) * 512 + nn) * 2048 + (sidx & ~31) + pos] = f2b(v);
          }
        }
      }
    }
  }
}

// ---------------- flash attention: 3-buffer counted-vmcnt pipeline ----------
// 1 block = 128 q rows of one (b,h); 4 waves x 32 q rows (2 x 16-row frags).
// KVTILE=64 keys. T3/T4 port: 2-deep prefetch into 3 LDS buffers, raw
// s_barrier + counted s_waitcnt vmcnt(4) (STAGE = 4 gload_lds per wave) so
// the per-iteration __syncthreads vmcnt(0) drain (round-1 diagnosis: ~4.2k
// cyc/iter vs ~1k of pipe work, duration invariant to per-wave efficiency)
// no longer serializes the L2 latency of the prefetch.
// Swapped QK^T: mfma(K,Q) -> P lane-local in PV A-frag layout; no online max
// (q pre-scaled by 0.125*log2e, |s|<~2 in log2 domain, exp2 overflow at 127).
__global__ __launch_bounds__(256) void attn_kernel(
    const u16* __restrict__ q, const u16* __restrict__ k,
    const u16* __restrict__ vt, u16* __restrict__ o)
{
  __shared__ u16 kls[3][64 * 64];              // 8KB per buf
  __shared__ u16 vls[3][64 * 64];              // 48KB total
  int t = threadIdx.x, lane = t & 63, w = t >> 6;
  int l15 = lane & 15, g = lane >> 4;
  int sw = l15 & 7;                            // ds_read swizzle key
  int lrow = lane >> 3;                        // staging: local row 0..7
  int lchunk = (lane & 7) ^ (lrow & 7);        // staging: pre-swizzled chunk
  // XCD-aware remap: each XCD sees 4 (b,h) pairs -> K/V L2-resident
  int fid = blockIdx.x + 32 * blockIdx.y;      // 0..511
  int xcd = fid & 7, rest = fid >> 3;
  int bh = xcd * 4 + (rest & 3);
  int qt = rest >> 2;                          // 0..15, q-tile of 128
  int bb = bh >> 3, h = bh & 7;
  int qbase = qt * 128 + w * 32;

  const u16* qp = q + (size_t)(bb * 2048 + qbase + l15) * 512 + h * 64 + g * 8;
  s16x8 qf0a = *(const s16x8*)qp;              // B-frag: lane&15 = q row
  s16x8 qf1a = *(const s16x8*)(qp + 32);
  s16x8 qf0b = *(const s16x8*)(qp + 16 * 512); // q-group 1: rows +16
  s16x8 qf1b = *(const s16x8*)(qp + 16 * 512 + 32);
  f32x4 zero = {0.0f, 0.0f, 0.0f, 0.0f};
  f32x4 oacc[2][4];
  #pragma unroll
  for (int qg = 0; qg < 2; ++qg)
    #pragma unroll
    for (int nf = 0; nf < 4; ++nf) oacc[qg][nf] = zero;
  float lsum[2] = {0.0f, 0.0f};                // per-lane partial row sums
  const u16* kb0 = k + (size_t)(bb * 2048) * 512 + h * 64;
  const u16* vb0 = vt + (size_t)((bb * 8 + h) * 64) * 2048;

  #define STAGE(nb, tt) do {                                                  \
    int sr0 = w * 16 + lrow;                                                  \
    const u16* ks0 = kb0 + (size_t)((tt) * 64 + sr0) * 512 + lchunk * 8;      \
    const u16* vs0 = vb0 + (size_t)sr0 * 2048 + (tt) * 64 + lchunk * 8;       \
    gload_lds16(ks0, &kls[nb][(w * 16) * 64]);                                \
    gload_lds16(ks0 + (size_t)8 * 512, &kls[nb][(w * 16 + 8) * 64]);          \
    gload_lds16(vs0, &vls[nb][(w * 16) * 64]);                                \
    gload_lds16(vs0 + (size_t)8 * 2048, &vls[nb][(w * 16 + 8) * 64]);         \
  } while (0)

  STAGE(0, 0);                                 // tiles 0,1 in flight
  STAGE(1, 1);
  int bi = 0;

  for (int kt = 0; kt < 32; ++kt) {
    // tile kt landed when <=4 of this wave's loads remain outstanding
    if (kt < 31) asm volatile("s_waitcnt vmcnt(4)" ::: "memory");
    else         asm volatile("s_waitcnt vmcnt(0)" ::: "memory");
    __builtin_amdgcn_s_barrier();              // + buf (bi+2)%3 free now
    if (kt + 2 < 32) {
      int pi = bi + 2; if (pi >= 3) pi -= 3;
      STAGE(pi, kt + 2);
    }
    const u16* kcur = kls[bi];
    const u16* vcur = vls[bi];
    f32x4 s[2][4];
    #pragma unroll
    for (int kg = 0; kg < 4; ++kg) {
      int rb = (kg * 16 + l15) * 64;
      s16x8 ka = *(const s16x8*)&kcur[rb + ((g ^ sw) << 3)];
      s16x8 kc = *(const s16x8*)&kcur[rb + (((4 + g) ^ sw) << 3)];
      s[0][kg] = mfma16(ka, qf0a, zero);       // S^T[key][q=l15], group 0
      s[0][kg] = mfma16(kc, qf1a, s[0][kg]);
      s[1][kg] = mfma16(ka, qf0b, zero);       // group 1 reuses ka/kc
      s[1][kg] = mfma16(kc, qf1b, s[1][kg]);
    }
    union { s16x8 v8; unsigned u32v[4]; } pk[2][2];
    #pragma unroll
    for (int qg = 0; qg < 2; ++qg) {
      #pragma unroll
      for (int b2 = 0; b2 < 2; ++b2) {
        #pragma unroll
        for (int r = 0; r < 4; ++r) {
          float p0 = __builtin_amdgcn_exp2f(s[qg][2 * b2][r]);
          float p1 = __builtin_amdgcn_exp2f(s[qg][2 * b2 + 1][r]);
          lsum[qg] += p0 + p1;
          union { float f; unsigned u; } a, b;
          a.f = p0; b.f = p1;
          // hi16(p1):hi16(p0) in one v_perm_b32 (bit-identical truncation)
          pk[qg][b2].u32v[r] = __builtin_amdgcn_perm(b.u, a.u, 0x07060302u);
        }
      }
    }
    #pragma unroll
    for (int b2 = 0; b2 < 2; ++b2) {
      #pragma unroll
      for (int nf = 0; nf < 4; ++nf) {
        s16x8 vf = *(const s16x8*)
            &vcur[(nf * 16 + l15) * 64 + ((((b2 << 2) | g) ^ sw) << 3)];
        oacc[0][nf] = mfma16(pk[0][b2].v8, vf, oacc[0][nf]);
        oacc[1][nf] = mfma16(pk[1][b2].v8, vf, oacc[1][nf]);
      }
    }
    bi = (bi == 2) ? 0 : bi + 1;
  }
  #undef STAGE

  #pragma unroll
  for (int qg = 0; qg < 2; ++qg) {
    float ls = lsum[qg];
    ls += __shfl_xor(ls, 16);                  // reduce across g-groups
    ls += __shfl_xor(ls, 32);
    float linv = 1.0f / ls;                    // valid for q = l15
    size_t obase = (size_t)(bb * 2048 + qbase + qg * 16 + 4 * g) * 512
                 + h * 64 + l15;
    #pragma unroll
    for (int r = 0; r < 4; ++r) {
      float lr = __shfl(linv, 4 * g + r);      // fetch l for q = 4g+r
      #pragma unroll
      for (int nf = 0; nf < 4; ++nf)
        o[obase + (size_t)r * 512 + nf * 16] = f2b(oacc[qg][nf][r] * lr);
    }
  }
}

// ---------------- launch ----------------------------------------------------
extern "C" void kernel_launch(void* const* d_in, const int* in_sizes, int n_in,
                              void* d_out, int out_size, void* d_ws, size_t ws_size,
                              hipStream_t stream)
{
  const float* x     = (const float*)d_in[0];
  const float* ln1_a = (const float*)d_in[1];
  const float* ln1_b = (const float*)d_in[2];
  const float* ln2_a = (const float*)d_in[3];
  const float* ln2_b = (const float*)d_in[4];
  const float* wq = (const float*)d_in[5];
  const float* wk = (const float*)d_in[6];
  const float* wv = (const float*)d_in[7];
  const float* wo = (const float*)d_in[8];
  const float* w1 = (const float*)d_in[9];
  const float* b1 = (const float*)d_in[10];
  const float* w2 = (const float*)d_in[11];
  const float* b2 = (const float*)d_in[12];

  char* ws = (char*)d_ws;                       // needs 75 MB
  float* xn_f = (float*)(ws + (size_t)0);       // 16 MB  LN1 out fp32 (resid)
  float* h_f  = (float*)(ws + ((size_t)16 << 20)); // 16 MB h fp32
  u16* xn_b = (u16*)(ws + ((size_t)32 << 20));  // 8 MB  LN1 out bf16
  u16* q_b  = (u16*)(ws + ((size_t)40 << 20));  // 8 MB  (reused as hn)
  u16* k_b  = (u16*)(ws + ((size_t)48 << 20));  // 8 MB
  u16* vt_b = (u16*)(ws + ((size_t)56 << 20));  // 8 MB  V^T [B,n,Sperm]
  u16* at_b = (u16*)(ws + ((size_t)64 << 20));  // 8 MB  (reused as ffn-mid)
  u16* wb   = (u16*)(ws + ((size_t)72 << 20));  // 3 MB  bf16 weights
  u16 *wob = wb + 3*262144, *w1b = wb + 4 * 262144, *w2b = wb + 5 * 262144;
  u16* hn_b = q_b;   // q dead after attention
  u16* f_b  = at_b;  // attn dead after WO

  dim3 blk(256);
  cast_w<<<dim3(256, 6), blk, 0, stream>>>(wq, wk, wv, wo, w1, w2, wb);
  ln_kernel<1, 1><<<dim3(2048), blk, 0, stream>>>(x, ln1_a, ln1_b, xn_f, xn_b);
  // fused QKV: W = [wq;wk;wv] (contiguous in wb), N=1536
  // q pre-scaled by (1/sqrt(64))*log2(e) so attn computes p = exp2(s) directly
  gemm128<64><<<dim3(64, 12), blk, 0, stream>>>(
      xn_b, wb, nullptr, nullptr, nullptr, q_b, k_b, vt_b, 0.18033688f);
  attn_kernel<<<dim3(32, 16), blk, 0, stream>>>(q_b, k_b, vt_b, at_b);
  gemm128<4 | 8><<<dim3(64, 4), blk, 0, stream>>>(
      at_b, wob, nullptr, xn_f, h_f, nullptr, nullptr, nullptr, 0.0f);
  ln_kernel<0, 1><<<dim3(2048), blk, 0, stream>>>(h_f, ln2_a, ln2_b, nullptr, hn_b);
  gemm128<1 | 2 | 16><<<dim3(64, 4), blk, 0, stream>>>(
      hn_b, w1b, b1, nullptr, nullptr, f_b, nullptr, nullptr, 0.0f);
  gemm128<1 | 4 | 8><<<dim3(64, 4), blk, 0, stream>>>(
      f_b, w2b, b2, h_f, (float*)d_out, nullptr, nullptr, nullptr, 0.0f);
}

// Round 3
// 133.538 us; speedup vs baseline: 1.0843x; 1.0843x over previous
//
#include <hip/hip_runtime.h>

// EncoderLayer: B=4, S=2048, D=512, H=8, HD=64. fp32 I/O, bf16 MFMA compute.
// M = B*S = 8192 tokens. GEMMs: [8192,*] = [8192,512] @ W[*,512]^T.

typedef short s16x8 __attribute__((ext_vector_type(8)));
typedef float f32x4 __attribute__((ext_vector_type(4)));
typedef unsigned short u16;
typedef u16 u16x4 __attribute__((ext_vector_type(4)));

__device__ __forceinline__ u16 f2b(float f) {          // fp32 -> bf16 RNE
  union { float f; unsigned u; } c; c.f = f;
  return (u16)((c.u + 0x7FFFu + ((c.u >> 16) & 1u)) >> 16);
}

__device__ __forceinline__ f32x4 mfma16(s16x8 a, s16x8 b, f32x4 c) {
  return __builtin_amdgcn_mfma_f32_16x16x32_bf16(a, b, c, 0, 0, 0);
}

// async global->LDS, 16B per lane; dest = wave-uniform base + lane*16
__device__ __forceinline__ void gload_lds16(const u16* g, u16* l) {
  __builtin_amdgcn_global_load_lds(
      (const __attribute__((address_space(1))) unsigned*)g,
      (__attribute__((address_space(3))) unsigned*)l, 16, 0, 0);
}

// ---------------- weight cast: 6 x [512x512] fp32 -> bf16 (contiguous dst) --
__global__ __launch_bounds__(256) void cast_w(
    const float* __restrict__ s0, const float* __restrict__ s1,
    const float* __restrict__ s2, const float* __restrict__ s3,
    const float* __restrict__ s4, const float* __restrict__ s5,
    u16* __restrict__ dst)
{
  int i = blockIdx.x * 256 + threadIdx.x;   // float4 index, 65536 per matrix
  const float* s;
  switch (blockIdx.y) {
    case 0: s = s0; break; case 1: s = s1; break; case 2: s = s2; break;
    case 3: s = s3; break; case 4: s = s4; break; default: s = s5; break;
  }
  float4 v = ((const float4*)s)[i];
  u16x4 o; o.x = f2b(v.x); o.y = f2b(v.y); o.z = f2b(v.z); o.w = f2b(v.w);
  *(u16x4*)(dst + (size_t)blockIdx.y * 262144 + (size_t)i * 4) = o;
}

// ---------------- LayerNorm (torch: unbiased var, a*(x-mean)/(std+eps)+b) ---
template<int OF, int OB>
__global__ __launch_bounds__(256) void ln_kernel(
    const float* __restrict__ x, const float* __restrict__ ga,
    const float* __restrict__ gbv, float* __restrict__ yf, u16* __restrict__ yb)
{
  int row = blockIdx.x * 4 + (threadIdx.x >> 6);   // one wave per row
  int lane = threadIdx.x & 63;
  size_t base = (size_t)row * 512 + lane * 8;
  const float4* xr = (const float4*)(x + base);
  float4 v0 = xr[0], v1 = xr[1];
  float s  = v0.x + v0.y + v0.z + v0.w + v1.x + v1.y + v1.z + v1.w;
  float ss = v0.x*v0.x + v0.y*v0.y + v0.z*v0.z + v0.w*v0.w
           + v1.x*v1.x + v1.y*v1.y + v1.z*v1.z + v1.w*v1.w;
  #pragma unroll
  for (int m = 1; m < 64; m <<= 1) { s += __shfl_xor(s, m); ss += __shfl_xor(ss, m); }
  float mean = s * (1.0f / 512.0f);
  float var  = fmaxf((ss - 512.0f * mean * mean) * (1.0f / 511.0f), 0.0f);
  float inv  = 1.0f / (sqrtf(var) + 1e-6f);
  const float4* ap = (const float4*)(ga + lane * 8);
  const float4* bp = (const float4*)(gbv + lane * 8);
  float4 a0 = ap[0], a1 = ap[1], b0 = bp[0], b1 = bp[1];
  float4 y0, y1;
  y0.x = (v0.x-mean)*inv*a0.x + b0.x;  y0.y = (v0.y-mean)*inv*a0.y + b0.y;
  y0.z = (v0.z-mean)*inv*a0.z + b0.z;  y0.w = (v0.w-mean)*inv*a0.w + b0.w;
  y1.x = (v1.x-mean)*inv*a1.x + b1.x;  y1.y = (v1.y-mean)*inv*a1.y + b1.y;
  y1.z = (v1.z-mean)*inv*a1.z + b1.z;  y1.w = (v1.w-mean)*inv*a1.w + b1.w;
  if (OF) { float4* o = (float4*)(yf + base); o[0] = y0; o[1] = y1; }
  if (OB) {
    union { s16x8 v; u16 u[8]; } pk;
    pk.u[0]=f2b(y0.x); pk.u[1]=f2b(y0.y); pk.u[2]=f2b(y0.z); pk.u[3]=f2b(y0.w);
    pk.u[4]=f2b(y1.x); pk.u[5]=f2b(y1.y); pk.u[6]=f2b(y1.z); pk.u[7]=f2b(y1.w);
    *(s16x8*)(yb + base) = pk.v;
  }
}

// ---------------- GEMM 128x128 tile (m97 structure) -------------------------
// C[8192,N] = A[8192,512](bf16) @ W[N,512]^T, N = 512 or 1536 (fused QKV).
// 4 waves (2x2), each owns 64x64; BK=32, double-buffered LDS staged via
// global_load_lds w=16; bank-swizzle chunk^=(row>>1)&3 on source + ds_read.
// (Round-2's counted-vmcnt port regressed the GEMMs ~5us total -> reverted.)
// MODE bits: 1=bias, 2=relu, 4=resid(fp32), 8=store f32, 16=store bf16,
//            64=fused QKV epilogue (q scaled, k plain, v permuted-transpose)
template<int MODE>
__global__ __launch_bounds__(256) void gemm128(
    const u16* __restrict__ A, const u16* __restrict__ W,
    const float* __restrict__ bias, const float* __restrict__ resid,
    float* __restrict__ outf, u16* __restrict__ outb,
    u16* __restrict__ outb2, u16* __restrict__ outb3, float qscale)
{
  __shared__ u16 als[2][128 * 32];             // 8KB per buf
  __shared__ u16 bls[2][128 * 32];
  int t = threadIdx.x, lane = t & 63, w = t >> 6;
  int l15 = lane & 15, g = lane >> 4;
  int wr = w >> 1, wc = w & 1;
  int mbase = blockIdx.x * 128, nbase = blockIdx.y * 128;

  // staging: chunkid = i*256+t -> row=cid>>2, phys chunk=cid&3,
  // source (logical) chunk = (cid&3) ^ ((row>>1)&3)
  int r0 = t >> 2, cs = (t & 3) ^ ((r0 >> 1) & 3);  // note: same cs for row+64
  size_t offA0 = (size_t)(mbase + r0) * 512 + cs * 8;
  size_t offA1 = (size_t)(mbase + r0 + 64) * 512 + cs * 8;
  size_t offB0 = (size_t)(nbase + r0) * 512 + cs * 8;
  size_t offB1 = (size_t)(nbase + r0 + 64) * 512 + cs * 8;

  #define GSTAGE(buf, k0) do {                                    \
    gload_lds16(A + (k0) + offA0, &als[buf][(w * 64) * 8]);       \
    gload_lds16(A + (k0) + offA1, &als[buf][(256 + w * 64) * 8]); \
    gload_lds16(W + (k0) + offB0, &bls[buf][(w * 64) * 8]);       \
    gload_lds16(W + (k0) + offB1, &bls[buf][(256 + w * 64) * 8]); \
  } while (0)

  // fragment ds_read offsets (u16 units), logical chunk g swizzled per row
  int ar[4], br[4];
  #pragma unroll
  for (int i = 0; i < 4; ++i) {
    int rA = wr * 64 + i * 16 + l15;
    ar[i] = rA * 32 + ((g ^ ((rA >> 1) & 3)) << 3);
    int rB = wc * 64 + i * 16 + l15;
    br[i] = rB * 32 + ((g ^ ((rB >> 1) & 3)) << 3);
  }

  f32x4 zero = {0.0f, 0.0f, 0.0f, 0.0f};
  f32x4 acc[4][4];
  #pragma unroll
  for (int mi = 0; mi < 4; ++mi)
    #pragma unroll
    for (int ni = 0; ni < 4; ++ni) acc[mi][ni] = zero;

  GSTAGE(0, 0);
  __syncthreads();
  int cur = 0;
  for (int kk = 0; kk < 16; ++kk) {
    if (kk < 15) GSTAGE(cur ^ 1, (kk + 1) * 32);   // prefetch next K-tile
    s16x8 af[4], bfr[4];
    #pragma unroll
    for (int i = 0; i < 4; ++i) {
      af[i]  = *(const s16x8*)&als[cur][ar[i]];
      bfr[i] = *(const s16x8*)&bls[cur][br[i]];
    }
    #pragma unroll
    for (int mi = 0; mi < 4; ++mi)
      #pragma unroll
      for (int ni = 0; ni < 4; ++ni)
        acc[mi][ni] = mfma16(af[mi], bfr[ni], acc[mi][ni]);
    __syncthreads();                               // prefetch landed, reads done
    cur ^= 1;
  }
  #undef GSTAGE

  #pragma unroll
  for (int ni = 0; ni < 4; ++ni) {
    int n = nbase + wc * 64 + ni * 16 + l15;
    float bv = (MODE & 1) ? bias[n] : 0.0f;
    #pragma unroll
    for (int mi = 0; mi < 4; ++mi) {
      #pragma unroll
      for (int r = 0; r < 4; ++r) {
        int m = mbase + wr * 64 + mi * 16 + 4 * g + r;  // D: col=l15, row=4g+r
        float v = acc[mi][ni][r] + bv;
        if (MODE & 2) v = fmaxf(v, 0.0f);
        if (MODE & 4) v += resid[(size_t)m * 512 + n];
        if (MODE & 8) outf[(size_t)m * 512 + n] = v;
        if (MODE & 16) outb[(size_t)m * 512 + n] = f2b(v);
        if (MODE & 64) {
          if (nbase < 512) {                       // Q (pre-scaled)
            outb[(size_t)m * 512 + n] = f2b(v * qscale);
          } else if (nbase < 1024) {               // K
            outb2[(size_t)m * 512 + (n - 512)] = f2b(v);
          } else {                                 // V^T with attn k-perm
            int nn = n - 1024;
            int sidx = m & 2047;
            int jj = sidx & 31, lo4 = jj & 15, b5 = jj >> 4;
            int pos = ((lo4 >> 2) << 3) + ((lo4 & 3) << 1) + b5;
            outb3[(size_t)((m >> 11) * 512 + nn) * 2048 + (sidx & ~31) + pos] = f2b(v);
          }
        }
      }
    }
  }
}

// ---------------- flash attention: QK^T-ahead software pipeline -------------
// 1 block = 128 q rows of one (b,h); 4 waves x 32 q rows (2 x 16-row frags).
// KVTILE=64. Rounds 0-2 post-mortem: per-iter pipes SERIALIZE (LDS ~1800 +
// VALU/trans ~2000 + MFMA ~1200 cyc/CU-iter SUM to the observed ~4300) --
// the chain dsread K -> QK^T -> exp2/pack -> PV never overlaps across pipes.
// Fix (T15): compute QK^T(kt+1) in the same scheduling region as
// softmax(kt)+PV(kt) -- independent dataflow, so trans/LDS/MFMA pipes overlap.
// Needs tile kt+1 readable while computing kt: 4 LDS buffers, 2-deep counted
// vmcnt prefetch (tile kt+2 stays in flight across barriers).
// Swapped QK^T: mfma(K,Q) -> P lane-local in PV A-frag layout; no online max
// (q pre-scaled by 0.125*log2e, |s|<~2 in log2 domain, exp2 overflow at 127).
__global__ __launch_bounds__(256) void attn_kernel(
    const u16* __restrict__ q, const u16* __restrict__ k,
    const u16* __restrict__ vt, u16* __restrict__ o)
{
  __shared__ u16 kls[4][64 * 64];              // 8KB per buf, 64KB total
  __shared__ u16 vls[4][64 * 64];
  int t = threadIdx.x, lane = t & 63, w = t >> 6;
  int l15 = lane & 15, g = lane >> 4;
  int sw = l15 & 7;                            // ds_read swizzle key
  int lrow = lane >> 3;                        // staging: local row 0..7
  int lchunk = (lane & 7) ^ (lrow & 7);        // staging: pre-swizzled chunk
  // XCD-aware remap: each XCD sees 4 (b,h) pairs -> K/V L2-resident
  int fid = blockIdx.x + 32 * blockIdx.y;      // 0..511
  int xcd = fid & 7, rest = fid >> 3;
  int bh = xcd * 4 + (rest & 3);
  int qt = rest >> 2;                          // 0..15, q-tile of 128
  int bb = bh >> 3, h = bh & 7;
  int qbase = qt * 128 + w * 32;

  const u16* qp = q + (size_t)(bb * 2048 + qbase + l15) * 512 + h * 64 + g * 8;
  s16x8 qf0a = *(const s16x8*)qp;              // B-frag: lane&15 = q row
  s16x8 qf1a = *(const s16x8*)(qp + 32);
  s16x8 qf0b = *(const s16x8*)(qp + 16 * 512); // q-group 1: rows +16
  s16x8 qf1b = *(const s16x8*)(qp + 16 * 512 + 32);
  f32x4 zero = {0.0f, 0.0f, 0.0f, 0.0f};
  f32x4 oacc[2][4];
  #pragma unroll
  for (int qg = 0; qg < 2; ++qg)
    #pragma unroll
    for (int nf = 0; nf < 4; ++nf) oacc[qg][nf] = zero;
  float lsum[2] = {0.0f, 0.0f};                // per-lane partial row sums
  const u16* kb0 = k + (size_t)(bb * 2048) * 512 + h * 64;
  const u16* vb0 = vt + (size_t)((bb * 8 + h) * 64) * 2048;

  #define STAGE(nb, tt) do {                                                  \
    int sr0 = w * 16 + lrow;                                                  \
    const u16* ks0 = kb0 + (size_t)((tt) * 64 + sr0) * 512 + lchunk * 8;      \
    const u16* vs0 = vb0 + (size_t)sr0 * 2048 + (tt) * 64 + lchunk * 8;       \
    gload_lds16(ks0, &kls[nb][(w * 16) * 64]);                                \
    gload_lds16(ks0 + (size_t)8 * 512, &kls[nb][(w * 16 + 8) * 64]);          \
    gload_lds16(vs0, &vls[nb][(w * 16) * 64]);                                \
    gload_lds16(vs0 + (size_t)8 * 2048, &vls[nb][(w * 16 + 8) * 64]);         \
  } while (0)

  // QK^T of one K-tile into sdst[2][4] (S^T[key][q=l15], both q-groups)
  #define QKT(kbuf, sdst) do {                                                \
    _Pragma("unroll")                                                         \
    for (int kg = 0; kg < 4; ++kg) {                                          \
      int rb = (kg * 16 + l15) * 64;                                          \
      s16x8 ka = *(const s16x8*)&(kbuf)[rb + ((g ^ sw) << 3)];                \
      s16x8 kc = *(const s16x8*)&(kbuf)[rb + (((4 + g) ^ sw) << 3)];          \
      sdst[0][kg] = mfma16(ka, qf0a, zero);                                   \
      sdst[0][kg] = mfma16(kc, qf1a, sdst[0][kg]);                            \
      sdst[1][kg] = mfma16(ka, qf0b, zero);                                   \
      sdst[1][kg] = mfma16(kc, qf1b, sdst[1][kg]);                            \
    }                                                                         \
  } while (0)

  // exp2 + bf16-pack of s-regs -> pk, accumulate lsum
  #define SMAX(ssrc) do {                                                     \
    _Pragma("unroll")                                                         \
    for (int qg = 0; qg < 2; ++qg) {                                          \
      _Pragma("unroll")                                                       \
      for (int b2 = 0; b2 < 2; ++b2) {                                        \
        _Pragma("unroll")                                                     \
        for (int r = 0; r < 4; ++r) {                                         \
          float p0 = __builtin_amdgcn_exp2f(ssrc[qg][2 * b2][r]);             \
          float p1 = __builtin_amdgcn_exp2f(ssrc[qg][2 * b2 + 1][r]);         \
          lsum[qg] += p0 + p1;                                                \
          union { float f; unsigned u; } ua, ub;                              \
          ua.f = p0; ub.f = p1;                                               \
          pk[qg][b2].u32v[r] = __builtin_amdgcn_perm(ub.u, ua.u, 0x07060302u);\
        }                                                                     \
      }                                                                       \
    }                                                                         \
  } while (0)

  #define PVC(vbuf) do {                                                      \
    _Pragma("unroll")                                                         \
    for (int b2 = 0; b2 < 2; ++b2) {                                          \
      _Pragma("unroll")                                                       \
      for (int nf = 0; nf < 4; ++nf) {                                        \
        s16x8 vf = *(const s16x8*)                                            \
            &(vbuf)[(nf * 16 + l15) * 64 + ((((b2 << 2) | g) ^ sw) << 3)];    \
        oacc[0][nf] = mfma16(pk[0][b2].v8, vf, oacc[0][nf]);                  \
        oacc[1][nf] = mfma16(pk[1][b2].v8, vf, oacc[1][nf]);                  \
      }                                                                       \
    }                                                                         \
  } while (0)

  typedef union { s16x8 v8; unsigned u32v[4]; } pku;

  // At top of ITER(kt): outstanding = own loads of tiles kt+1,kt+2 (4 each).
  // vmcnt(4) -> tile kt+1 landed (kt+2 stays in flight). Tail: kt>=30 ->
  // only tile 31 outstanding -> vmcnt(0). STAGE(kt+3) overwrites slot
  // (kt-1)&3: its reads (V at iter kt-1) were consumed by MFMAs (compiler
  // lgkmcnt before use) before each wave's barrier arrival -> safe.
  #define ITER(kt, scur, snxt) do {                                           \
    if ((kt) < 30) asm volatile("s_waitcnt vmcnt(4)" ::: "memory");           \
    else           asm volatile("s_waitcnt vmcnt(0)" ::: "memory");           \
    __builtin_amdgcn_s_barrier();                                             \
    if ((kt) + 3 < 32) STAGE(((kt) + 3) & 3, (kt) + 3);                       \
    if ((kt) + 1 < 32) QKT(kls[((kt) + 1) & 3], snxt);                        \
    pku pk[2][2];                                                             \
    SMAX(scur);                                                               \
    PVC(vls[(kt) & 3]);                                                       \
  } while (0)

  STAGE(0, 0);                                 // tiles 0,1,2 in flight
  STAGE(1, 1);
  STAGE(2, 2);
  asm volatile("s_waitcnt vmcnt(8)" ::: "memory");   // tile 0 landed (own)
  __builtin_amdgcn_s_barrier();                      // -> landed for all waves
  f32x4 sA[2][4], sB[2][4];
  QKT(kls[0], sA);                             // prologue QK^T(0)

  for (int k2 = 0; k2 < 32; k2 += 2) {         // 2x unroll: sA/sB role swap
    ITER(k2, sA, sB);
    ITER(k2 + 1, sB, sA);
  }
  #undef ITER
  #undef PVC
  #undef SMAX
  #undef QKT
  #undef STAGE

  #pragma unroll
  for (int qg = 0; qg < 2; ++qg) {
    float ls = lsum[qg];
    ls += __shfl_xor(ls, 16);                  // reduce across g-groups
    ls += __shfl_xor(ls, 32);
    float linv = 1.0f / ls;                    // valid for q = l15
    size_t obase = (size_t)(bb * 2048 + qbase + qg * 16 + 4 * g) * 512
                 + h * 64 + l15;
    #pragma unroll
    for (int r = 0; r < 4; ++r) {
      float lr = __shfl(linv, 4 * g + r);      // fetch l for q = 4g+r
      #pragma unroll
      for (int nf = 0; nf < 4; ++nf)
        o[obase + (size_t)r * 512 + nf * 16] = f2b(oacc[qg][nf][r] * lr);
    }
  }
}

// ---------------- launch ----------------------------------------------------
extern "C" void kernel_launch(void* const* d_in, const int* in_sizes, int n_in,
                              void* d_out, int out_size, void* d_ws, size_t ws_size,
                              hipStream_t stream)
{
  const float* x     = (const float*)d_in[0];
  const float* ln1_a = (const float*)d_in[1];
  const float* ln1_b = (const float*)d_in[2];
  const float* ln2_a = (const float*)d_in[3];
  const float* ln2_b = (const float*)d_in[4];
  const float* wq = (const float*)d_in[5];
  const float* wk = (const float*)d_in[6];
  const float* wv = (const float*)d_in[7];
  const float* wo = (const float*)d_in[8];
  const float* w1 = (const float*)d_in[9];
  const float* b1 = (const float*)d_in[10];
  const float* w2 = (const float*)d_in[11];
  const float* b2 = (const float*)d_in[12];

  char* ws = (char*)d_ws;                       // needs 75 MB
  float* xn_f = (float*)(ws + (size_t)0);       // 16 MB  LN1 out fp32 (resid)
  float* h_f  = (float*)(ws + ((size_t)16 << 20)); // 16 MB h fp32
  u16* xn_b = (u16*)(ws + ((size_t)32 << 20));  // 8 MB  LN1 out bf16
  u16* q_b  = (u16*)(ws + ((size_t)40 << 20));  // 8 MB  (reused as hn)
  u16* k_b  = (u16*)(ws + ((size_t)48 << 20));  // 8 MB
  u16* vt_b = (u16*)(ws + ((size_t)56 << 20));  // 8 MB  V^T [B,n,Sperm]
  u16* at_b = (u16*)(ws + ((size_t)64 << 20));  // 8 MB  (reused as ffn-mid)
  u16* wb   = (u16*)(ws + ((size_t)72 << 20));  // 3 MB  bf16 weights
  u16 *wob = wb + 3*262144, *w1b = wb + 4 * 262144, *w2b = wb + 5 * 262144;
  u16* hn_b = q_b;   // q dead after attention
  u16* f_b  = at_b;  // attn dead after WO

  dim3 blk(256);
  cast_w<<<dim3(256, 6), blk, 0, stream>>>(wq, wk, wv, wo, w1, w2, wb);
  ln_kernel<1, 1><<<dim3(2048), blk, 0, stream>>>(x, ln1_a, ln1_b, xn_f, xn_b);
  // fused QKV: W = [wq;wk;wv] (contiguous in wb), N=1536
  // q pre-scaled by (1/sqrt(64))*log2(e) so attn computes p = exp2(s) directly
  gemm128<64><<<dim3(64, 12), blk, 0, stream>>>(
      xn_b, wb, nullptr, nullptr, nullptr, q_b, k_b, vt_b, 0.18033688f);
  attn_kernel<<<dim3(32, 16), blk, 0, stream>>>(q_b, k_b, vt_b, at_b);
  gemm128<4 | 8><<<dim3(64, 4), blk, 0, stream>>>(
      at_b, wob, nullptr, xn_f, h_f, nullptr, nullptr, nullptr, 0.0f);
  ln_kernel<0, 1><<<dim3(2048), blk, 0, stream>>>(h_f, ln2_a, ln2_b, nullptr, hn_b);
  gemm128<1 | 2 | 16><<<dim3(64, 4), blk, 0, stream>>>(
      hn_b, w1b, b1, nullptr, nullptr, f_b, nullptr, nullptr, 0.0f);
  gemm128<1 | 4 | 8><<<dim3(64, 4), blk, 0, stream>>>(
      f_b, w2b, b2, h_f, (float*)d_out, nullptr, nullptr, nullptr, 0.0f);
}